// Round 3
// baseline (427.286 us; speedup 1.0000x reference)
//
#include <hip/hip_runtime.h>
#include <math.h>

// B=8, N1=64, N2=4096, C=768, H=12, hd=64, scale=1/8.
// Pipeline (all big GEMMs bf16-MFMA, softmax math fp32):
//   cast_all: x,Wqkv,Wproj,y -> bf16 (one kernel)
//   qkv_gemm: KV [32768,1536] = ybf @ Wkv^T (1536 blocks) + Q [512,768] = xbf @ Wq^T (12 blocks)
//   pass1 (MFMA S=QK^T) -> per-chunk (max,sumexp) partials
//   pass2 (MFMA S) -> inline combine of partials -> Ebf[key, h*64+j] = softmax_p * V
//   out_gemm [32768,768] = Ebf @ Wproj^T + b (f32 out)
// GEMM core: 256x128 tile, BK=32, 4 waves each owning 128x64 C (acc[8][4]),
// 2-buffer global_load_lds staging with 1 __syncthreads per K-iter (proven
// round-1 sync structure; only tile geometry changed: 32 MFMA / 12 ds_read
// per wave-iter vs 16/8 before).
// Granule rotation sigma_r(c) = (c + (r>>1)) & 3 -> balanced LDS banks
// (measured 0 conflicts), gl_lds-compatible via pre-swizzled global source.

typedef __attribute__((ext_vector_type(8))) short short8;
typedef __attribute__((ext_vector_type(4))) float f32x4;

__device__ __forceinline__ ushort f2bf(float x) {
  unsigned u = __float_as_uint(x);
  u += 0x7fffu + ((u >> 16) & 1u);          // round-to-nearest-even
  return (ushort)(u >> 16);
}
__device__ __forceinline__ float bf2f(ushort h) {
  return __uint_as_float((unsigned)h << 16);
}

// async global->LDS, 16B per lane; LDS dest = wave-uniform base + lane*16
__device__ __forceinline__ void gl_lds16(const ushort* g, ushort* l) {
  __builtin_amdgcn_global_load_lds(
      (__attribute__((address_space(1))) void*)g,
      (__attribute__((address_space(3))) void*)l, 16, 0, 0);
}

// ---------------- fused fp32 -> bf16 casts, 8 elems/thread ----------------
// element ranges (all multiples of 8): x 393216 | Wqkv 1769472 | Wproj 589824 | y 25165824
__global__ __launch_bounds__(256) void cast_all(
    const float* __restrict__ x, ushort* __restrict__ xb,
    const float* __restrict__ w1, ushort* __restrict__ w1b,
    const float* __restrict__ w2, ushort* __restrict__ w2b,
    const float* __restrict__ y, ushort* __restrict__ yb) {
  long i = (long)(blockIdx.x * 256 + threadIdx.x) * 8;
  if (i >= 27918336L) return;
  const float* s; ushort* d; long off;
  if (i < 393216L)        { s = x;  d = xb;  off = i; }
  else if (i < 2162688L)  { s = w1; d = w1b; off = i - 393216L; }
  else if (i < 2752512L)  { s = w2; d = w2b; off = i - 2162688L; }
  else                    { s = y;  d = yb;  off = i - 2752512L; }
  float4 a = *(const float4*)(s + off);
  float4 b = *(const float4*)(s + off + 4);
  ushort o[8] = {f2bf(a.x), f2bf(a.y), f2bf(a.z), f2bf(a.w),
                 f2bf(b.x), f2bf(b.y), f2bf(b.z), f2bf(b.w)};
  *(uint4*)(d + off) = *(const uint4*)o;
}

// ---------------- bf16 MFMA GEMM body: 256x128 C tile = A[256,K] @ B[128,K]^T ----------------
template <typename CT>
__device__ __forceinline__ void gemm_body(
    const ushort* __restrict__ A, int lda,
    const ushort* __restrict__ B, int ldb,
    CT* __restrict__ C, int ldc, int K,
    const float* __restrict__ bias, int rt, int ct)
{
  __shared__ __align__(16) ushort As[2][8192];   // 256 rows x 32 cols, granule-rotated
  __shared__ __align__(16) ushort Bs[2][4096];   // 128 rows x 32 cols
  const int tid = threadIdx.x;
  const int m0 = rt * 256, n0 = ct * 128;

  const int w = tid >> 6, lane = tid & 63;
  const int lm = lane & 15, quad = lane >> 4;
  const int WR = (w >> 1) * 128, WC = (w & 1) * 64;   // wave C: rows [WR,WR+128), cols [WC,WC+64)

  // staging geometry: linear granule G -> (row = G>>2, pos = G&3),
  // stored[row][pos] = src granule (pos - (row>>1)) & 3  (inverse of read rotation)
  const ushort* Ag[4];
#pragma unroll
  for (int q = 0; q < 4; ++q) {
    const int G = q * 256 + w * 64 + lane;
    const int row = G >> 2, g = ((G & 3) - (row >> 1)) & 3;
    Ag[q] = A + (size_t)(m0 + row) * lda + g * 8;
  }
  const ushort* Bg[2];
#pragma unroll
  for (int q = 0; q < 2; ++q) {
    const int G = q * 256 + w * 64 + lane;
    const int row = G >> 2, g = ((G & 3) - (row >> 1)) & 3;
    Bg[q] = B + (size_t)(n0 + row) * ldb + g * 8;
  }

  f32x4 acc[8][4];
#pragma unroll
  for (int i = 0; i < 8; ++i)
#pragma unroll
    for (int j = 0; j < 4; ++j) acc[i][j] = (f32x4)(0.f);

  const int nk = K >> 5;
  // prologue: stage tile 0 -> buf0 (wave-uniform LDS dests; lane offset implicit)
#pragma unroll
  for (int q = 0; q < 4; ++q) gl_lds16(Ag[q], &As[0][q * 2048 + w * 512]);
#pragma unroll
  for (int q = 0; q < 2; ++q) gl_lds16(Bg[q], &Bs[0][q * 2048 + w * 512]);

  int cur = 0;
  for (int kk = 0; kk < nk; ++kk) {
    __syncthreads();   // drains vmcnt: buf[cur] ready; prev reads of buf[cur^1] done
    if (kk + 1 < nk) {
      const int k0 = (kk + 1) << 5;
#pragma unroll
      for (int q = 0; q < 4; ++q) gl_lds16(Ag[q] + k0, &As[cur ^ 1][q * 2048 + w * 512]);
#pragma unroll
      for (int q = 0; q < 2; ++q) gl_lds16(Bg[q] + k0, &Bs[cur ^ 1][q * 2048 + w * 512]);
    }
    const ushort* Ab = &As[cur][0];
    const ushort* Bb = &Bs[cur][0];
    short8 af[8], bf8[4];
#pragma unroll
    for (int i = 0; i < 8; ++i) {
      const int Ra = WR + i * 16 + lm;
      af[i] = *(const short8*)(const void*)(Ab + Ra * 32 + ((quad + (Ra >> 1)) & 3) * 8);
    }
#pragma unroll
    for (int j = 0; j < 4; ++j) {
      const int Rb = WC + j * 16 + lm;
      bf8[j] = *(const short8*)(const void*)(Bb + Rb * 32 + ((quad + (Rb >> 1)) & 3) * 8);
    }
#pragma unroll
    for (int i = 0; i < 8; ++i)
#pragma unroll
      for (int j = 0; j < 4; ++j)
        acc[i][j] = __builtin_amdgcn_mfma_f32_16x16x32_bf16(af[i], bf8[j], acc[i][j], 0, 0, 0);
    cur ^= 1;
  }
  __syncthreads();   // LDS free for epilogue scratch; all loads drained

  if constexpr (sizeof(CT) == 2) {
    // bf16 out: LDS-bounce to coalesced dwordx4 stores. 4KB scratch/wave in As.
    ushort* eb = ((ushort*)&As[0][0]) + w * 2048;
#pragma unroll
    for (int i = 0; i < 8; ++i) {
      ushort* ebc = eb + (i & 1) * 1024;    // ping-pong between chunks
#pragma unroll
      for (int j = 0; j < 4; ++j)
#pragma unroll
        for (int r = 0; r < 4; ++r) {
          const int R = quad * 4 + r;
          const int gt = j * 2 + (lm >> 3);
          const int gs = (gt + R) & 7;      // granule swizzle
          ebc[R * 64 + gs * 8 + (lm & 7)] = f2bf(acc[i][j][r]);
        }
#pragma unroll
      for (int p = 0; p < 2; ++p) {
        const int R2 = (lane >> 3) + p * 8;
        const int g = lane & 7;
        const int gt2 = (g - R2) & 7;
        uint4 v = *(const uint4*)(const void*)(ebc + R2 * 64 + g * 8);
        *(uint4*)(C + (size_t)(m0 + WR + i * 16 + R2) * ldc + n0 + WC + gt2 * 8) = v;
      }
    }
  } else {
    // f32 out + bias
#pragma unroll
    for (int j = 0; j < 4; ++j) {
      const int col = n0 + WC + j * 16 + lm;
      const float bb = bias ? bias[col] : 0.f;
#pragma unroll
      for (int i = 0; i < 8; ++i) {
        const int row = m0 + WR + i * 16 + quad * 4;
#pragma unroll
        for (int r = 0; r < 4; ++r)
          C[(size_t)(row + r) * ldc + col] = (CT)(acc[i][j][r] + bb);
      }
    }
  }
}

// ---------------- fused QKV projections: KV (1536 blocks, XCD-swz) + Q (12 blocks) ----------------
__global__ __launch_bounds__(256, 2) void qkv_gemm(
    const ushort* __restrict__ xbf, const ushort* __restrict__ ybf,
    const ushort* __restrict__ wqkv, ushort* __restrict__ qbf,
    ushort* __restrict__ kvbf)
{
  const int id = blockIdx.x;
  if (id < 1536) {
    // KV: m_tiles=128 (256 rows each), n_tiles=12; 16 row-tiles per XCD band
    const int xcd = id & 7, local = id >> 3;
    const int rt = xcd * 16 + (local & 15);
    const int ct = local >> 4;
    gemm_body<ushort>(ybf, 768, wqkv + (size_t)768 * 768, 768, kvbf, 1536, 768,
                      nullptr, rt, ct);
  } else {
    // Q: m_tiles=2, n_tiles=6
    const int q = id - 1536;
    gemm_body<ushort>(xbf, 768, wqkv, 768, qbf, 768, 768, nullptr, q & 1, q >> 1);
  }
}

// ---------------- out = Ebf @ Wproj^T + b (f32 out, 768 blocks, XCD-swz) ----------------
__global__ __launch_bounds__(256, 2) void out_gemm(
    const ushort* __restrict__ Ebf, const ushort* __restrict__ wpbf,
    const float* __restrict__ bias, float* __restrict__ out)
{
  const int id = blockIdx.x;            // m_tiles=128, n_tiles=6
  const int xcd = id & 7, local = id >> 3;
  const int rt = xcd * 16 + (local & 15);
  const int ct = local >> 4;
  gemm_body<float>(Ebf, 768, wpbf, 768, out, 768, 768, bias, rt, ct);
}

// ---------------- pass 1: MFMA S=QK^T, per-chunk (max,sumexp) ----------------
// grid (32 chunks, 12 h, 8 b), 256 threads. Wave w: keys [w*32, w*32+32).
__global__ __launch_bounds__(256) void attn_pass1(
    const ushort* __restrict__ Q,     // [512,768] bf16
    const ushort* __restrict__ KV,    // [32768,1536] bf16, K cols 0..767
    float* __restrict__ parts)        // [96][32][64][2]
{
  const int chunk = blockIdx.x, h = blockIdx.y, b = blockIdx.z;
  const int tid = threadIdx.x;
  __shared__ __align__(16) ushort Qs[64 * 72];
  __shared__ __align__(16) ushort Ks[128 * 72];
  __shared__ float sm[4][64], ss[4][64];
#pragma unroll
  for (int p = 0; p < 2; ++p) {
    const int G = tid + 256 * p, row = G >> 3, g = G & 7;
    *(uint4*)(Qs + row * 72 + g * 8) =
        *(const uint4*)(Q + (size_t)(b * 64 + row) * 768 + h * 64 + g * 8);
  }
#pragma unroll
  for (int p = 0; p < 4; ++p) {
    const int G = tid + 256 * p, row = G >> 3, g = G & 7;
    *(uint4*)(Ks + row * 72 + g * 8) =
        *(const uint4*)(KV + (size_t)(b * 4096 + chunk * 128 + row) * 1536 + h * 64 + g * 8);
  }
  __syncthreads();

  const int w = tid >> 6, lane = tid & 63;
  const int lm = lane & 15, quad = lane >> 4;
  const int wn = w * 32;

  f32x4 acc[4][2];
#pragma unroll
  for (int i = 0; i < 4; ++i) { acc[i][0] = (f32x4)(0.f); acc[i][1] = (f32x4)(0.f); }
#pragma unroll
  for (int s = 0; s < 2; ++s) {
    short8 qf[4], kf[2];
#pragma unroll
    for (int i = 0; i < 4; ++i)
      qf[i] = *(const short8*)(const void*)(Qs + (i * 16 + lm) * 72 + s * 32 + quad * 8);
#pragma unroll
    for (int jn = 0; jn < 2; ++jn)
      kf[jn] = *(const short8*)(const void*)(Ks + (wn + jn * 16 + lm) * 72 + s * 32 + quad * 8);
#pragma unroll
    for (int i = 0; i < 4; ++i)
#pragma unroll
      for (int jn = 0; jn < 2; ++jn)
        acc[i][jn] = __builtin_amdgcn_mfma_f32_16x16x32_bf16(qf[i], kf[jn], acc[i][jn], 0, 0, 0);
  }

#pragma unroll
  for (int i = 0; i < 4; ++i)
#pragma unroll
    for (int r = 0; r < 4; ++r) {
      float v0 = acc[i][0][r] * 0.125f, v1 = acc[i][1][r] * 0.125f;
      float m = fmaxf(v0, v1);
      m = fmaxf(m, __shfl_xor(m, 1)); m = fmaxf(m, __shfl_xor(m, 2));
      m = fmaxf(m, __shfl_xor(m, 4)); m = fmaxf(m, __shfl_xor(m, 8));
      float e = __expf(v0 - m) + __expf(v1 - m);
      e += __shfl_xor(e, 1); e += __shfl_xor(e, 2);
      e += __shfl_xor(e, 4); e += __shfl_xor(e, 8);
      if (lm == 0) {
        const int j = i * 16 + quad * 4 + r;
        sm[w][j] = m; ss[w][j] = e;
      }
    }
  __syncthreads();
  if (tid < 64) {
    float g = fmaxf(fmaxf(sm[0][tid], sm[1][tid]), fmaxf(sm[2][tid], sm[3][tid]));
    float s = ss[0][tid] * __expf(sm[0][tid] - g) + ss[1][tid] * __expf(sm[1][tid] - g)
            + ss[2][tid] * __expf(sm[2][tid] - g) + ss[3][tid] * __expf(sm[3][tid] - g);
    const int bh = b * 12 + h;
    float* p = parts + ((size_t)(bh * 32 + chunk) * 64 + tid) * 2;
    p[0] = g; p[1] = s;
  }
}

// ---------------- pass 2: inline combine + MFMA S, Ebf[key, h*64+j] = p * V ----------------
__global__ __launch_bounds__(256) void attn_pass2(
    const ushort* __restrict__ Q, const ushort* __restrict__ KV,
    const float* __restrict__ parts, ushort* __restrict__ E)
{
  const int chunk = blockIdx.x, h = blockIdx.y, b = blockIdx.z;
  const int tid = threadIdx.x;
  __shared__ __align__(16) ushort Qs[64 * 72];
  __shared__ __align__(16) ushort Ks[128 * 72];
  __shared__ __align__(16) ushort Vs[128 * 72];
  __shared__ float st[64][2];
#pragma unroll
  for (int p = 0; p < 2; ++p) {
    const int G = tid + 256 * p, row = G >> 3, g = G & 7;
    *(uint4*)(Qs + row * 72 + g * 8) =
        *(const uint4*)(Q + (size_t)(b * 64 + row) * 768 + h * 64 + g * 8);
  }
#pragma unroll
  for (int p = 0; p < 4; ++p) {
    const int G = tid + 256 * p, row = G >> 3, g = G & 7;
    const size_t rbase = (size_t)(b * 4096 + chunk * 128 + row) * 1536 + h * 64 + g * 8;
    *(uint4*)(Ks + row * 72 + g * 8) = *(const uint4*)(KV + rbase);
    *(uint4*)(Vs + row * 72 + g * 8) = *(const uint4*)(KV + rbase + 768);
  }
  // inline combine: 4 threads per query row, 8 chunks each (parts is L2/L3-resident)
  {
    const int bh = b * 12 + h;
    const int tq = tid >> 2, tc = tid & 3;
    float pm[8], ps[8];
    float gm = -1e30f;
#pragma unroll
    for (int c = 0; c < 8; ++c) {
      const float* p = parts + ((size_t)(bh * 32 + tc * 8 + c) * 64 + tq) * 2;
      pm[c] = p[0]; ps[c] = p[1];
      gm = fmaxf(gm, pm[c]);
    }
    gm = fmaxf(gm, __shfl_xor(gm, 1));
    gm = fmaxf(gm, __shfl_xor(gm, 2));
    float s = 0.f;
#pragma unroll
    for (int c = 0; c < 8; ++c) s += ps[c] * __expf(pm[c] - gm);
    s += __shfl_xor(s, 1);
    s += __shfl_xor(s, 2);
    if (tc == 0) { st[tq][0] = gm; st[tq][1] = 1.f / s; }
  }
  __syncthreads();

  const int w = tid >> 6, lane = tid & 63;
  const int lm = lane & 15, quad = lane >> 4;
  const int wn = w * 32;

  f32x4 acc[4][2];
#pragma unroll
  for (int i = 0; i < 4; ++i) { acc[i][0] = (f32x4)(0.f); acc[i][1] = (f32x4)(0.f); }
#pragma unroll
  for (int s = 0; s < 2; ++s) {
    short8 qf[4], kf[2];
#pragma unroll
    for (int i = 0; i < 4; ++i)
      qf[i] = *(const short8*)(const void*)(Qs + (i * 16 + lm) * 72 + s * 32 + quad * 8);
#pragma unroll
    for (int jn = 0; jn < 2; ++jn)
      kf[jn] = *(const short8*)(const void*)(Ks + (wn + jn * 16 + lm) * 72 + s * 32 + quad * 8);
#pragma unroll
    for (int i = 0; i < 4; ++i)
#pragma unroll
      for (int jn = 0; jn < 2; ++jn)
        acc[i][jn] = __builtin_amdgcn_mfma_f32_16x16x32_bf16(qf[i], kf[jn], acc[i][jn], 0, 0, 0);
  }

  ushort ev[4][2][4];
#pragma unroll
  for (int i = 0; i < 4; ++i)
#pragma unroll
    for (int jn = 0; jn < 2; ++jn)
#pragma unroll
      for (int r = 0; r < 4; ++r) {
        const float v = acc[i][jn][r] * 0.125f;
        const int j = i * 16 + quad * 4 + r;
        const float p = __expf(v - st[j][0]) * st[j][1];
        const int key = wn + jn * 16 + lm;
        ev[i][jn][r] = f2bf(p * bf2f(Vs[key * 72 + j]));
      }
  __syncthreads();                 // all frag reads of Ks done -> reuse as E staging
  ushort* Es = Ks;
#pragma unroll
  for (int i = 0; i < 4; ++i)
#pragma unroll
    for (int jn = 0; jn < 2; ++jn)
#pragma unroll
      for (int r = 0; r < 4; ++r)
        Es[(wn + jn * 16 + lm) * 72 + i * 16 + quad * 4 + r] = ev[i][jn][r];
  __syncthreads();
#pragma unroll
  for (int k = 0; k < 4; ++k) {
    const int row = tid >> 1, g = (tid & 1) * 4 + k;
    uint4 v = *(const uint4*)(const void*)(Es + row * 72 + g * 8);
    *(uint4*)(E + (size_t)(b * 4096 + chunk * 128 + row) * 768 + h * 64 + g * 8) = v;
  }
}

extern "C" void kernel_launch(void* const* d_in, const int* in_sizes, int n_in,
                              void* d_out, int out_size, void* d_ws, size_t ws_size,
                              hipStream_t stream) {
  const float* x     = (const float*)d_in[0];   // [8,64,768]
  const float* y     = (const float*)d_in[1];   // [8,4096,768]
  const float* Wqkv  = (const float*)d_in[2];   // [2304,768]
  const float* Wproj = (const float*)d_in[3];   // [768,768]
  const float* bproj = (const float*)d_in[4];   // [768]
  float* out = (float*)d_out;                   // [8,4096,768]

  // workspace layout (bytes), total 157,286,400:
  //   xbf    bf16 [512,768]    @ 0
  //   qbf    bf16 [512,768]    @ 786432
  //   wqkvbf bf16 [2304,768]   @ 1572864   (dead after qkv_gemm)
  //     parts f32 [96,32,64,2] @ 1572864   (alias, used after)
  //   wpbf   bf16 [768,768]    @ 5111808
  //   ybf/Ebf bf16 [32768,768] @ 6291456   (Ebf aliases dead ybf)
  //   KVbf   bf16 [32768,1536] @ 56623104
  char* wsb = (char*)d_ws;
  ushort* xbf    = (ushort*)(wsb + 0);
  ushort* qbf    = (ushort*)(wsb + 786432);
  ushort* wqkvbf = (ushort*)(wsb + 1572864);
  float*  parts  = (float*)(wsb + 1572864);
  ushort* wpbf   = (ushort*)(wsb + 5111808);
  ushort* ybf    = (ushort*)(wsb + 6291456);
  ushort* Ebf    = ybf;
  ushort* KVbf   = (ushort*)(wsb + 56623104);

  // all casts in one launch: 27,918,336 elems / 8 per thread / 256 per block
  cast_all<<<13632, 256, 0, stream>>>(x, xbf, Wqkv, wqkvbf, Wproj, wpbf, y, ybf);

  // KV projection (1536 blocks) + Q projection (12 blocks) in one launch
  qkv_gemm<<<1548, 256, 0, stream>>>(xbf, ybf, wqkvbf, qbf, KVbf);

  // softmax stats (two-pass flash style, MFMA S); combine folded into pass2
  attn_pass1<<<dim3(32, 12, 8), 256, 0, stream>>>(qbf, KVbf, parts);
  attn_pass2<<<dim3(32, 12, 8), 256, 0, stream>>>(qbf, KVbf, parts, Ebf);

  // out = Ebf @ Wproj^T + b (f32 out)
  out_gemm<<<768, 256, 0, stream>>>(Ebf, wpbf, bproj, out);
}

// Round 5
// 413.341 us; speedup vs baseline: 1.0337x; 1.0337x over previous
//
#include <hip/hip_runtime.h>
#include <math.h>

// B=8, N1=64, N2=4096, C=768, H=12, hd=64, scale=1/8.
// Pipeline:
//   cast_all: x,Wqkv,Wproj,y -> bf16 (one kernel)
//   q_gemm:   Q [512,768] = xbf @ Wq^T          (24 blocks, proven 128^2 2-buffer core)
//   kv_gemm8: KV [32768,1536] = ybf @ Wkv^T     (768 blocks, 256^2 8-phase core)
//   pass1 (MFMA S=QK^T) -> per-chunk (max,sumexp) partials
//   pass2 (MFMA S) -> inline combine -> Ebf[key, h*64+j] = softmax_p * V
//   out_gemm8 [32768,768] = Ebf @ Wproj^T + b   (384 blocks, 256^2 8-phase core)
//
// 8-phase core (T2+T3+T4+T5 port): BM=BN=256, BK=64, 512 thr = 8 waves (2Mx4N),
// per-wave C 128x64 (acc[8][4]). LDS 128KB = 2dbuf x (A 256x64 + B 256x64) bf16.
// Per K-tile: 4 phases {ds_read subtile; stage 1 half-tile (2 gl_lds); barrier;
// MFMA x16 under setprio(1); barrier}. Staging schedule (derived-waits):
//   ph0/ph1: A halves of K-tile T+1 -> other buffer (freed at end of T-1)
//   ph2/ph3: B halves of K-tile T+2 -> same buffer (B fully read in ph0)
// vmcnt(4) once per K-tile (before the ph3-ending barrier): forces A(T+1),B(T+1)
// landed, leaves B(T+2)'s 4 loads in flight across the barrier (never drains).
// LDS swizzle: granule' = granule ^ (row&7) (read side); gl_lds writes linearly,
// so the global SOURCE is pre-swizzled with the same involution (rule #21).
// -> ds_read_b128: 8 lanes per 16B granule-column = wave64 minimum (conflict-free).

typedef __attribute__((ext_vector_type(8))) short short8;
typedef __attribute__((ext_vector_type(4))) float f32x4;

__device__ __forceinline__ ushort f2bf(float x) {
  unsigned u = __float_as_uint(x);
  u += 0x7fffu + ((u >> 16) & 1u);          // round-to-nearest-even
  return (ushort)(u >> 16);
}
__device__ __forceinline__ float bf2f(ushort h) {
  return __uint_as_float((unsigned)h << 16);
}

// async global->LDS, 16B per lane; LDS dest = wave-uniform base + lane*16
__device__ __forceinline__ void gl_lds16(const ushort* g, ushort* l) {
  __builtin_amdgcn_global_load_lds(
      (__attribute__((address_space(1))) void*)g,
      (__attribute__((address_space(3))) void*)l, 16, 0, 0);
}

// ---------------- fused fp32 -> bf16 casts, 8 elems/thread ----------------
__global__ __launch_bounds__(256) void cast_all(
    const float* __restrict__ x, ushort* __restrict__ xb,
    const float* __restrict__ w1, ushort* __restrict__ w1b,
    const float* __restrict__ w2, ushort* __restrict__ w2b,
    const float* __restrict__ y, ushort* __restrict__ yb) {
  long i = (long)(blockIdx.x * 256 + threadIdx.x) * 8;
  if (i >= 27918336L) return;
  const float* s; ushort* d; long off;
  if (i < 393216L)        { s = x;  d = xb;  off = i; }
  else if (i < 2162688L)  { s = w1; d = w1b; off = i - 393216L; }
  else if (i < 2752512L)  { s = w2; d = w2b; off = i - 2162688L; }
  else                    { s = y;  d = yb;  off = i - 2752512L; }
  float4 a = *(const float4*)(s + off);
  float4 b = *(const float4*)(s + off + 4);
  ushort o[8] = {f2bf(a.x), f2bf(a.y), f2bf(a.z), f2bf(a.w),
                 f2bf(b.x), f2bf(b.y), f2bf(b.z), f2bf(b.w)};
  *(uint4*)(d + off) = *(const uint4*)o;
}

// ================= 256x256 8-phase MFMA GEMM core =================
// C[256,256] tile = A[256,K] @ B[256,K]^T, K=768 (NK=12 K-tiles of 64).
template <typename CT>
__device__ __forceinline__ void gemm8_body(
    const ushort* __restrict__ A, int lda,
    const ushort* __restrict__ B, int ldb,
    CT* __restrict__ C, int ldc,
    const float* __restrict__ bias, int rt, int ct)
{
  constexpr int NK = 12;
  __shared__ __align__(16) ushort Abuf[2][16384];   // [256][64] swizzled
  __shared__ __align__(16) ushort Bbuf[2][16384];
  const int tid = threadIdx.x;                      // 0..511
  const int m0 = rt * 256, n0 = ct * 256;
  const int wv = tid >> 6, lane = tid & 63;
  const int lm = lane & 15, quad = lane >> 4;
  const int WR = (wv >> 2) * 128, WC = (wv & 3) * 64;

  // staging source pointers: instruction j covers LDS rows (wv*4+j)*8 .. +8;
  // source granule pre-swizzled: g_src = (lane&7) ^ (row&7), row&7 = lane>>3.
  const int srow = lane >> 3;                  // 0..7
  const int sg = (lane & 7) ^ srow;            // pre-swizzled source granule
  const ushort* Ag[4];
  const ushort* Bg[4];
#pragma unroll
  for (int j = 0; j < 4; ++j) {
    const int r = (wv * 4 + j) * 8 + srow;     // 0..255
    Ag[j] = A + (size_t)(m0 + r) * lda + sg * 8;
    Bg[j] = B + (size_t)(n0 + r) * ldb + sg * 8;
  }

  f32x4 acc[8][4];
#pragma unroll
  for (int i = 0; i < 8; ++i)
#pragma unroll
    for (int j = 0; j < 4; ++j) acc[i][j] = (f32x4)(0.f);

  // prologue: stage A(0)->Abuf0, B(0)->Bbuf0, B(1)->Bbuf1 (12 loads/thread)
#pragma unroll
  for (int j = 0; j < 4; ++j) gl_lds16(Ag[j], &Abuf[0][(wv * 4 + j) * 512]);
#pragma unroll
  for (int j = 0; j < 4; ++j) gl_lds16(Bg[j], &Bbuf[0][(wv * 4 + j) * 512]);
#pragma unroll
  for (int j = 0; j < 4; ++j) gl_lds16(Bg[j] + 64, &Bbuf[1][(wv * 4 + j) * 512]);
  asm volatile("s_waitcnt vmcnt(4)" ::: "memory");  // A(0),B(0) landed; B(1) in flight
  __builtin_amdgcn_s_barrier();

#pragma unroll 1
  for (int T = 0; T < NK; ++T) {
    const ushort* Ab = &Abuf[T & 1][0];
    const ushort* Bb = &Bbuf[T & 1][0];
    ushort* An = &Abuf[(T & 1) ^ 1][0];   // dest for A(T+1)
    ushort* Bn = &Bbuf[T & 1][0];         // dest for B(T+2) (same parity)
    const int k1 = (T + 1) * 64, k2 = (T + 2) * 64;
    const bool stA = (T + 1 < NK), stB = (T + 2 < NK);
    short8 bfr[4][2];

#pragma unroll
    for (int q = 0; q < 4; ++q) {
      // ---- ds-read register subtile ----
      if (q == 0) {
#pragma unroll
        for (int n = 0; n < 4; ++n)
#pragma unroll
          for (int ks = 0; ks < 2; ++ks)
            bfr[n][ks] = *(const short8*)(const void*)(
                Bb + (WC + n * 16 + lm) * 64 + ((ks * 4 + quad) ^ (lm & 7)) * 8);
      }
      short8 af[2][2];
#pragma unroll
      for (int i = 0; i < 2; ++i)
#pragma unroll
        for (int ks = 0; ks < 2; ++ks)
          af[i][ks] = *(const short8*)(const void*)(
              Ab + (WR + (q * 2 + i) * 16 + lm) * 64 + ((ks * 4 + quad) ^ (lm & 7)) * 8);
      // ---- stage one half-tile (2 gl_lds) ----
      if (q == 0 && stA) { gl_lds16(Ag[0] + k1, An + (wv * 4 + 0) * 512);
                           gl_lds16(Ag[1] + k1, An + (wv * 4 + 1) * 512); }
      if (q == 1 && stA) { gl_lds16(Ag[2] + k1, An + (wv * 4 + 2) * 512);
                           gl_lds16(Ag[3] + k1, An + (wv * 4 + 3) * 512); }
      if (q == 2 && stB) { gl_lds16(Bg[0] + k2, Bn + (wv * 4 + 0) * 512);
                           gl_lds16(Bg[1] + k2, Bn + (wv * 4 + 1) * 512); }
      if (q == 3 && stB) { gl_lds16(Bg[2] + k2, Bn + (wv * 4 + 2) * 512);
                           gl_lds16(Bg[3] + k2, Bn + (wv * 4 + 3) * 512); }
      __builtin_amdgcn_s_barrier();
      // ---- MFMA cluster: C rows {2q,2q+1}x16, all 4 n-frags, K=64 ----
      __builtin_amdgcn_s_setprio(1);
#pragma unroll
      for (int i = 0; i < 2; ++i)
#pragma unroll
        for (int n = 0; n < 4; ++n)
#pragma unroll
          for (int ks = 0; ks < 2; ++ks)
            acc[q * 2 + i][n] = __builtin_amdgcn_mfma_f32_16x16x32_bf16(
                af[i][ks], bfr[n][ks], acc[q * 2 + i][n], 0, 0, 0);
      __builtin_amdgcn_s_setprio(0);
      if (q == 3) {
        if (stB) asm volatile("s_waitcnt vmcnt(4)" ::: "memory");
        else     asm volatile("s_waitcnt vmcnt(0)" ::: "memory");
      }
      __builtin_amdgcn_s_barrier();
    }
  }
  __syncthreads();   // drain everything; LDS free for epilogue scratch

  if constexpr (sizeof(CT) == 2) {
    // bf16 out: LDS-bounce to coalesced dwordx4 stores (proven epilogue).
    ushort* eb = ((ushort*)&Abuf[0][0]) + wv * 2048;
#pragma unroll
    for (int i = 0; i < 8; ++i) {
      ushort* ebc = eb + (i & 1) * 1024;
#pragma unroll
      for (int j = 0; j < 4; ++j)
#pragma unroll
        for (int r = 0; r < 4; ++r) {
          const int R = quad * 4 + r;
          const int gt = j * 2 + (lm >> 3);
          const int gs = (gt + R) & 7;
          ebc[R * 64 + gs * 8 + (lm & 7)] = f2bf(acc[i][j][r]);
        }
#pragma unroll
      for (int p = 0; p < 2; ++p) {
        const int R2 = (lane >> 3) + p * 8;
        const int g = lane & 7;
        const int gt2 = (g - R2) & 7;
        uint4 v = *(const uint4*)(const void*)(ebc + R2 * 64 + g * 8);
        *(uint4*)(C + (size_t)(m0 + WR + i * 16 + R2) * ldc + n0 + WC + gt2 * 8) = v;
      }
    }
  } else {
    // f32 out + bias
#pragma unroll
    for (int j = 0; j < 4; ++j) {
      const int col = n0 + WC + j * 16 + lm;
      const float bb = bias ? bias[col] : 0.f;
#pragma unroll
      for (int i = 0; i < 8; ++i) {
        const int row = m0 + WR + i * 16 + quad * 4;
#pragma unroll
        for (int r = 0; r < 4; ++r)
          C[(size_t)(row + r) * ldc + col] = (CT)(acc[i][j][r] + bb);
      }
    }
  }
}

// KV projection: 768 blocks = 8 XCDs x (16 rt x 6 ct); exactly 3 rounds of 256 CUs.
__global__ __launch_bounds__(512, 2) void kv_gemm8(
    const ushort* __restrict__ ybf, const ushort* __restrict__ wkv,
    ushort* __restrict__ kvbf)
{
  const int id = blockIdx.x;
  const int xcd = id & 7, local = id >> 3;     // local 0..95
  const int rt = xcd * 16 + (local & 15);      // 0..127
  const int ct = local >> 4;                   // 0..5
  gemm8_body<ushort>(ybf, 768, wkv, 768, kvbf, 1536, nullptr, rt, ct);
}

// out = Ebf @ Wproj^T + b: 384 blocks = 8 x (16 rt x 3 ct)
__global__ __launch_bounds__(512, 2) void out_gemm8(
    const ushort* __restrict__ Ebf, const ushort* __restrict__ wpbf,
    const float* __restrict__ bias, float* __restrict__ out)
{
  const int id = blockIdx.x;
  const int xcd = id & 7, local = id >> 3;     // local 0..47
  const int rt = xcd * 16 + (local & 15);      // 0..127
  const int ct = local >> 4;                   // 0..2
  gemm8_body<float>(Ebf, 768, wpbf, 768, out, 768, bias, rt, ct);
}

// ---------------- Q projection: proven round-1 128^2 2-buffer core, 24 blocks ----------------
__global__ __launch_bounds__(256) void q_gemm(
    const ushort* __restrict__ A, const ushort* __restrict__ B,
    ushort* __restrict__ C)
{
  constexpr int lda = 768, ldb = 768, ldc = 768, K = 768;
  __shared__ __align__(16) ushort As[2][4096];
  __shared__ __align__(16) ushort Bs[2][4096];
  const int tid = threadIdx.x;
  const int rt = blockIdx.x & 3, ct = blockIdx.x >> 2;
  const int m0 = rt * 128, n0 = ct * 128;

  const int w = tid >> 6, lane = tid & 63;
  const int lm = lane & 15, quad = lane >> 4;
  const int wm = (w & 1) * 64, wn = (w >> 1) * 64;

  const int G0 = w * 64 + lane, G1 = G0 + 256;
  const int r0 = G0 >> 2, c0 = ((G0 & 3) - (r0 >> 1)) & 3;
  const int r1 = G1 >> 2, c1 = ((G1 & 3) - (r1 >> 1)) & 3;
  const ushort* Ag0 = A + (size_t)(m0 + r0) * lda + c0 * 8;
  const ushort* Ag1 = A + (size_t)(m0 + r1) * lda + c1 * 8;
  const ushort* Bg0 = B + (size_t)(n0 + r0) * ldb + c0 * 8;
  const ushort* Bg1 = B + (size_t)(n0 + r1) * ldb + c1 * 8;
  const int lds0 = w * 512, lds1 = w * 512 + 2048;

  f32x4 acc[4][4];
#pragma unroll
  for (int i = 0; i < 4; ++i)
#pragma unroll
    for (int j = 0; j < 4; ++j) acc[i][j] = (f32x4)(0.f);

  const int nk = K >> 5;
  gl_lds16(Ag0, &As[0][lds0]); gl_lds16(Ag1, &As[0][lds1]);
  gl_lds16(Bg0, &Bs[0][lds0]); gl_lds16(Bg1, &Bs[0][lds1]);

  int cur = 0;
  for (int kk = 0; kk < nk; ++kk) {
    __syncthreads();
    if (kk + 1 < nk) {
      const int k0 = (kk + 1) << 5;
      gl_lds16(Ag0 + k0, &As[cur ^ 1][lds0]); gl_lds16(Ag1 + k0, &As[cur ^ 1][lds1]);
      gl_lds16(Bg0 + k0, &Bs[cur ^ 1][lds0]); gl_lds16(Bg1 + k0, &Bs[cur ^ 1][lds1]);
    }
    const ushort* Ab = &As[cur][0];
    const ushort* Bb = &Bs[cur][0];
    short8 af[4], bf8[4];
#pragma unroll
    for (int i = 0; i < 4; ++i) {
      const int Ra = wm + i * 16 + lm;
      af[i] = *(const short8*)(const void*)(Ab + Ra * 32 + ((quad + (Ra >> 1)) & 3) * 8);
      const int Rb = wn + i * 16 + lm;
      bf8[i] = *(const short8*)(const void*)(Bb + Rb * 32 + ((quad + (Rb >> 1)) & 3) * 8);
    }
#pragma unroll
    for (int i = 0; i < 4; ++i)
#pragma unroll
      for (int j = 0; j < 4; ++j)
        acc[i][j] = __builtin_amdgcn_mfma_f32_16x16x32_bf16(af[i], bf8[j], acc[i][j], 0, 0, 0);
    cur ^= 1;
  }
  __syncthreads();

  ushort* eb = ((ushort*)&Bs[0][0]) + w * 2048;
#pragma unroll
  for (int i = 0; i < 4; ++i) {
    ushort* ebc = eb + (i & 1) * 1024;
#pragma unroll
    for (int j = 0; j < 4; ++j)
#pragma unroll
      for (int r = 0; r < 4; ++r) {
        const int R = quad * 4 + r;
        const int gt = j * 2 + (lm >> 3);
        const int gs = (gt + R) & 7;
        ebc[R * 64 + gs * 8 + (lm & 7)] = f2bf(acc[i][j][r]);
      }
#pragma unroll
    for (int p = 0; p < 2; ++p) {
      const int R2 = (lane >> 3) + p * 8;
      const int g = lane & 7;
      const int gt2 = (g - R2) & 7;
      uint4 v = *(const uint4*)(const void*)(ebc + R2 * 64 + g * 8);
      *(uint4*)(C + (size_t)(m0 + wm + i * 16 + R2) * ldc + n0 + wn + gt2 * 8) = v;
    }
  }
}

// ---------------- pass 1: MFMA S=QK^T, per-chunk (max,sumexp) ----------------
__global__ __launch_bounds__(256) void attn_pass1(
    const ushort* __restrict__ Q,     // [512,768] bf16
    const ushort* __restrict__ KV,    // [32768,1536] bf16, K cols 0..767
    float* __restrict__ parts)        // [96][32][64][2]
{
  const int chunk = blockIdx.x, h = blockIdx.y, b = blockIdx.z;
  const int tid = threadIdx.x;
  __shared__ __align__(16) ushort Qs[64 * 72];
  __shared__ __align__(16) ushort Ks[128 * 72];
  __shared__ float sm[4][64], ss[4][64];
#pragma unroll
  for (int p = 0; p < 2; ++p) {
    const int G = tid + 256 * p, row = G >> 3, g = G & 7;
    *(uint4*)(Qs + row * 72 + g * 8) =
        *(const uint4*)(Q + (size_t)(b * 64 + row) * 768 + h * 64 + g * 8);
  }
#pragma unroll
  for (int p = 0; p < 4; ++p) {
    const int G = tid + 256 * p, row = G >> 3, g = G & 7;
    *(uint4*)(Ks + row * 72 + g * 8) =
        *(const uint4*)(KV + (size_t)(b * 4096 + chunk * 128 + row) * 1536 + h * 64 + g * 8);
  }
  __syncthreads();

  const int w = tid >> 6, lane = tid & 63;
  const int lm = lane & 15, quad = lane >> 4;
  const int wn = w * 32;

  f32x4 acc[4][2];
#pragma unroll
  for (int i = 0; i < 4; ++i) { acc[i][0] = (f32x4)(0.f); acc[i][1] = (f32x4)(0.f); }
#pragma unroll
  for (int s = 0; s < 2; ++s) {
    short8 qf[4], kf[2];
#pragma unroll
    for (int i = 0; i < 4; ++i)
      qf[i] = *(const short8*)(const void*)(Qs + (i * 16 + lm) * 72 + s * 32 + quad * 8);
#pragma unroll
    for (int jn = 0; jn < 2; ++jn)
      kf[jn] = *(const short8*)(const void*)(Ks + (wn + jn * 16 + lm) * 72 + s * 32 + quad * 8);
#pragma unroll
    for (int i = 0; i < 4; ++i)
#pragma unroll
      for (int jn = 0; jn < 2; ++jn)
        acc[i][jn] = __builtin_amdgcn_mfma_f32_16x16x32_bf16(qf[i], kf[jn], acc[i][jn], 0, 0, 0);
  }

#pragma unroll
  for (int i = 0; i < 4; ++i)
#pragma unroll
    for (int r = 0; r < 4; ++r) {
      float v0 = acc[i][0][r] * 0.125f, v1 = acc[i][1][r] * 0.125f;
      float m = fmaxf(v0, v1);
      m = fmaxf(m, __shfl_xor(m, 1)); m = fmaxf(m, __shfl_xor(m, 2));
      m = fmaxf(m, __shfl_xor(m, 4)); m = fmaxf(m, __shfl_xor(m, 8));
      float e = __expf(v0 - m) + __expf(v1 - m);
      e += __shfl_xor(e, 1); e += __shfl_xor(e, 2);
      e += __shfl_xor(e, 4); e += __shfl_xor(e, 8);
      if (lm == 0) {
        const int j = i * 16 + quad * 4 + r;
        sm[w][j] = m; ss[w][j] = e;
      }
    }
  __syncthreads();
  if (tid < 64) {
    float g = fmaxf(fmaxf(sm[0][tid], sm[1][tid]), fmaxf(sm[2][tid], sm[3][tid]));
    float s = ss[0][tid] * __expf(sm[0][tid] - g) + ss[1][tid] * __expf(sm[1][tid] - g)
            + ss[2][tid] * __expf(sm[2][tid] - g) + ss[3][tid] * __expf(sm[3][tid] - g);
    const int bh = b * 12 + h;
    float* p = parts + ((size_t)(bh * 32 + chunk) * 64 + tid) * 2;
    p[0] = g; p[1] = s;
  }
}

// ---------------- pass 2: inline combine + MFMA S, Ebf[key, h*64+j] = p * V ----------------
__global__ __launch_bounds__(256) void attn_pass2(
    const ushort* __restrict__ Q, const ushort* __restrict__ KV,
    const float* __restrict__ parts, ushort* __restrict__ E)
{
  const int chunk = blockIdx.x, h = blockIdx.y, b = blockIdx.z;
  const int tid = threadIdx.x;
  __shared__ __align__(16) ushort Qs[64 * 72];
  __shared__ __align__(16) ushort Ks[128 * 72];
  __shared__ __align__(16) ushort Vs[128 * 72];
  __shared__ float st[64][2];
#pragma unroll
  for (int p = 0; p < 2; ++p) {
    const int G = tid + 256 * p, row = G >> 3, g = G & 7;
    *(uint4*)(Qs + row * 72 + g * 8) =
        *(const uint4*)(Q + (size_t)(b * 64 + row) * 768 + h * 64 + g * 8);
  }
#pragma unroll
  for (int p = 0; p < 4; ++p) {
    const int G = tid + 256 * p, row = G >> 3, g = G & 7;
    const size_t rbase = (size_t)(b * 4096 + chunk * 128 + row) * 1536 + h * 64 + g * 8;
    *(uint4*)(Ks + row * 72 + g * 8) = *(const uint4*)(KV + rbase);
    *(uint4*)(Vs + row * 72 + g * 8) = *(const uint4*)(KV + rbase + 768);
  }
  // inline combine: 4 threads per query row, 8 chunks each
  {
    const int bh = b * 12 + h;
    const int tq = tid >> 2, tc = tid & 3;
    float pm[8], ps[8];
    float gm = -1e30f;
#pragma unroll
    for (int c = 0; c < 8; ++c) {
      const float* p = parts + ((size_t)(bh * 32 + tc * 8 + c) * 64 + tq) * 2;
      pm[c] = p[0]; ps[c] = p[1];
      gm = fmaxf(gm, pm[c]);
    }
    gm = fmaxf(gm, __shfl_xor(gm, 1));
    gm = fmaxf(gm, __shfl_xor(gm, 2));
    float s = 0.f;
#pragma unroll
    for (int c = 0; c < 8; ++c) s += ps[c] * __expf(pm[c] - gm);
    s += __shfl_xor(s, 1);
    s += __shfl_xor(s, 2);
    if (tc == 0) { st[tq][0] = gm; st[tq][1] = 1.f / s; }
  }
  __syncthreads();

  const int w = tid >> 6, lane = tid & 63;
  const int lm = lane & 15, quad = lane >> 4;
  const int wn = w * 32;

  f32x4 acc[4][2];
#pragma unroll
  for (int i = 0; i < 4; ++i) { acc[i][0] = (f32x4)(0.f); acc[i][1] = (f32x4)(0.f); }
#pragma unroll
  for (int s = 0; s < 2; ++s) {
    short8 qf[4], kf[2];
#pragma unroll
    for (int i = 0; i < 4; ++i)
      qf[i] = *(const short8*)(const void*)(Qs + (i * 16 + lm) * 72 + s * 32 + quad * 8);
#pragma unroll
    for (int jn = 0; jn < 2; ++jn)
      kf[jn] = *(const short8*)(const void*)(Ks + (wn + jn * 16 + lm) * 72 + s * 32 + quad * 8);
#pragma unroll
    for (int i = 0; i < 4; ++i)
#pragma unroll
      for (int jn = 0; jn < 2; ++jn)
        acc[i][jn] = __builtin_amdgcn_mfma_f32_16x16x32_bf16(qf[i], kf[jn], acc[i][jn], 0, 0, 0);
  }

  ushort ev[4][2][4];
#pragma unroll
  for (int i = 0; i < 4; ++i)
#pragma unroll
    for (int jn = 0; jn < 2; ++jn)
#pragma unroll
      for (int r = 0; r < 4; ++r) {
        const float v = acc[i][jn][r] * 0.125f;
        const int j = i * 16 + quad * 4 + r;
        const float p = __expf(v - st[j][0]) * st[j][1];
        const int key = wn + jn * 16 + lm;
        ev[i][jn][r] = f2bf(p * bf2f(Vs[key * 72 + j]));
      }
  __syncthreads();                 // all frag reads of Ks done -> reuse as E staging
  ushort* Es = Ks;
#pragma unroll
  for (int i = 0; i < 4; ++i)
#pragma unroll
    for (int jn = 0; jn < 2; ++jn)
#pragma unroll
      for (int r = 0; r < 4; ++r)
        Es[(wn + jn * 16 + lm) * 72 + i * 16 + quad * 4 + r] = ev[i][jn][r];
  __syncthreads();
#pragma unroll
  for (int k = 0; k < 4; ++k) {
    const int row = tid >> 1, g = (tid & 1) * 4 + k;
    uint4 v = *(const uint4*)(const void*)(Es + row * 72 + g * 8);
    *(uint4*)(E + (size_t)(b * 4096 + chunk * 128 + row) * 768 + h * 64 + g * 8) = v;
  }
}

extern "C" void kernel_launch(void* const* d_in, const int* in_sizes, int n_in,
                              void* d_out, int out_size, void* d_ws, size_t ws_size,
                              hipStream_t stream) {
  const float* x     = (const float*)d_in[0];   // [8,64,768]
  const float* y     = (const float*)d_in[1];   // [8,4096,768]
  const float* Wqkv  = (const float*)d_in[2];   // [2304,768]
  const float* Wproj = (const float*)d_in[3];   // [768,768]
  const float* bproj = (const float*)d_in[4];   // [768]
  float* out = (float*)d_out;                   // [8,4096,768]

  // workspace layout (bytes), total 157,286,400:
  //   xbf    bf16 [512,768]    @ 0
  //   qbf    bf16 [512,768]    @ 786432
  //   wqkvbf bf16 [2304,768]   @ 1572864   (dead after gemms)
  //     parts f32 [96,32,64,2] @ 1572864   (alias, used after)
  //   wpbf   bf16 [768,768]    @ 5111808
  //   ybf/Ebf bf16 [32768,768] @ 6291456   (Ebf aliases dead ybf)
  //   KVbf   bf16 [32768,1536] @ 56623104
  char* wsb = (char*)d_ws;
  ushort* xbf    = (ushort*)(wsb + 0);
  ushort* qbf    = (ushort*)(wsb + 786432);
  ushort* wqkvbf = (ushort*)(wsb + 1572864);
  float*  parts  = (float*)(wsb + 1572864);
  ushort* wpbf   = (ushort*)(wsb + 5111808);
  ushort* ybf    = (ushort*)(wsb + 6291456);
  ushort* Ebf    = ybf;
  ushort* KVbf   = (ushort*)(wsb + 56623104);

  // all casts in one launch
  cast_all<<<13632, 256, 0, stream>>>(x, xbf, Wqkv, wqkvbf, Wproj, wpbf, y, ybf);

  // Q projection (tiny, proven 128^2 core)
  q_gemm<<<24, 256, 0, stream>>>(xbf, wqkvbf, qbf);

  // KV projection: 8-phase 256^2 core, 768 blocks = exactly 3 CU-rounds
  kv_gemm8<<<768, 512, 0, stream>>>(ybf, wqkvbf + (size_t)768 * 768, KVbf);

  // softmax stats (two-pass flash style, MFMA S); combine folded into pass2
  attn_pass1<<<dim3(32, 12, 8), 256, 0, stream>>>(qbf, KVbf, parts);
  attn_pass2<<<dim3(32, 12, 8), 256, 0, stream>>>(qbf, KVbf, parts, Ebf);

  // out = Ebf @ Wproj^T + b (f32 out), 8-phase core
  out_gemm8<<<384, 512, 0, stream>>>(Ebf, wpbf, bproj, out);
}